// Round 10
// baseline (93.283 us; speedup 1.0000x reference)
//
#include <hip/hip_runtime.h>
#include <hip/hip_fp16.h>
#include <cstdint>

#define HH 128
#define WW 128
#define NBATCH 2
#define CIN 256
#define COUT 256
#define DGN 4
#define K2 9
#define HW (HH*WW)
#define KTOT (K2*CIN)          // 2304, K index = dg*576 + tap*64 + c (dg-major)
#define NKS (KTOT/16)          // 144 k16-slices
#define NMT32 (COUT/32)        // 8 m-tiles of 32
#define NKP 36                 // k-pairs (64 ch each) = dg*9 + tap
// window: rows h-2..h+2 (5), cols w0-2..w0+65 (68)
#define WROWS 5
#define WCOLS 68
#define WPX (WROWS*WCOLS)      // 340 pixels, 128B each -> 43520 B

typedef __attribute__((ext_vector_type(8))) short short8;
typedef __attribute__((ext_vector_type(8))) _Float16 f16x8;
typedef __attribute__((ext_vector_type(16))) float f32x16;

struct __align__(16) H2x4 { __half2 h[4]; };

#define LGKM0() asm volatile("s_waitcnt lgkmcnt(0)" ::: "memory")
#define RAWBAR() do { LGKM0(); __builtin_amdgcn_s_barrier(); } while (0)
#define SB0() __builtin_amdgcn_sched_barrier(0)

static __device__ __forceinline__ unsigned short f2h_u(float f) {
    _Float16 h = (_Float16)f;
    return __builtin_bit_cast(unsigned short, h);
}

// ---- prologue 1: NCHW fp32 -> NHWC fp16 (xT[n][p][c], 512B per pixel) ----
__global__ __launch_bounds__(256) void tr_kernel(const float* __restrict__ x,
                                                 unsigned short* __restrict__ xT) {
    __shared__ float tile[64][65];
    const int b  = blockIdx.x;
    const int pt = b & 255;
    const int ct = (b >> 8) & 3;
    const int n  = b >> 10;
    const int p0 = pt * 64, c0 = ct * 64;
    const float* xn = x + (size_t)n * CIN * HW;
    const int tid = threadIdx.x;
    {
        const int tx = tid & 63, ty = tid >> 6;
        #pragma unroll
        for (int i = 0; i < 16; ++i) {
            int ch = i * 4 + ty;
            tile[ch][tx] = xn[(size_t)(c0 + ch) * HW + p0 + tx];
        }
    }
    __syncthreads();
    char* xb = (char*)xT + (size_t)n * HW * 512;
    {
        const int cx = tid & 31, pq = tid >> 5;
        #pragma unroll
        for (int i = 0; i < 8; ++i) {
            int p = i * 8 + pq;
            unsigned lo = f2h_u(tile[2 * cx][p]);
            unsigned hi = f2h_u(tile[2 * cx + 1][p]);
            *(unsigned*)(xb + (size_t)(p0 + p) * 512 + c0 * 2 + cx * 4) = lo | (hi << 16);
        }
    }
}

// ---- prologue 2: weights -> 32x32x16 A-fragments, dg-major K ordering ----
__global__ void wa_kernel(const float* __restrict__ w, unsigned int* __restrict__ wA) {
    int t = blockIdx.x * blockDim.x + threadIdx.x;
    if (t >= NKS * NMT32 * 64 * 4) return;
    int r  = t & 3;
    int l  = (t >> 2) & 63;
    int mt = (t >> 8) & 7;
    int ks = t >> 11;
    int m  = mt * 32 + (l & 31);
    int k0 = ks * 16 + (l >> 5) * 8 + r * 2;
    unsigned int pk = 0;
    #pragma unroll
    for (int e = 0; e < 2; ++e) {
        int k = k0 + e;                 // dg-major index
        int dg  = k / 576;
        int rem = k - dg * 576;
        int tap = rem >> 6;
        int c   = dg * 64 + (rem & 63);
        float v = w[(size_t)m * (CIN * K2) + c * 9 + tap];
        pk |= ((unsigned int)f2h_u(v)) << (16 * e);
    }
    wA[t] = pk;
}

// ---- prologue 3: coordinate/weight tables (16B per (tile,dgk,px)) ----
// e.x = pl0 | escape<<31 ; e.y = w00|w01<<16 ; e.z = w10|w11<<16 (validity-folded f16)
__global__ __launch_bounds__(256) void coord_kernel(const float* __restrict__ shape,
                                                    const float* __restrict__ wo,
                                                    uint4* __restrict__ tab) {
    const int tile = blockIdx.x;
    const int wh = tile & 1;
    const int h  = (tile >> 1) & 127;
    const int n  = tile >> 8;
    const int w0 = wh * 64;
    const int ybase = h - 2, xbase = w0 - 2;
    for (int s = threadIdx.x; s < DGN * K2 * 64; s += 256) {
        int p64 = s & 63;
        int dgk = s >> 6;
        int tap = dgk % 9;
        int w   = w0 + p64;
        float s0 = shape[((size_t)(n * 2 + 0)) * HW + h * WW + w];
        float s1 = shape[((size_t)(n * 2 + 1)) * HW + h * WW + w];
        float dy = wo[dgk * 4 + 0] * s0 + wo[dgk * 4 + 1] * s1;
        float dx = wo[dgk * 4 + 2] * s0 + wo[dgk * 4 + 3] * s1;
        float py  = (float)(h + (tap / 3) - 1) + dy;
        float pxf = (float)(w + (tap % 3) - 1) + dx;
        float y0f = floorf(py), x0f = floorf(pxf);
        float ly = py - y0f, lx = pxf - x0f;
        int y0 = (int)y0f, x0 = (int)x0f;
        int y0r = y0 - ybase, x0r = x0 - xbase;
        bool esc = ((unsigned)y0r > 3u) | ((unsigned)x0r > 66u);
        // image-validity factorized per row/col, folded into weights
        float vy0 = (y0 >= 0 && y0 <= HH - 1) ? 1.f : 0.f;
        float vy1 = (y0 + 1 >= 0 && y0 + 1 <= HH - 1) ? 1.f : 0.f;
        float vx0 = (x0 >= 0 && x0 <= WW - 1) ? 1.f : 0.f;
        float vx1 = (x0 + 1 >= 0 && x0 + 1 <= WW - 1) ? 1.f : 0.f;
        float wy0 = (1.f - ly) * vy0, wy1 = ly * vy1;
        float wx0 = (1.f - lx) * vx0, wx1 = lx * vx1;
        unsigned w00 = f2h_u(wy0 * wx0), w01 = f2h_u(wy0 * wx1);
        unsigned w10 = f2h_u(wy1 * wx0), w11 = f2h_u(wy1 * wx1);
        uint4 e;
        e.x = (unsigned)(esc ? 0 : (y0r * WCOLS + x0r)) | (esc ? 0x80000000u : 0u);
        e.y = w00 | (w01 << 16);
        e.z = w10 | (w11 << 16);
        e.w = 0;
        tab[(size_t)tile * (DGN * K2 * 64) + s] = e;
    }
}

// ---- main: 8 waves, 64 px, M=256; table-driven builds; LDS window gathers ----
__global__ __launch_bounds__(512, 4) void deform_mfma_kernel(
    const unsigned short* __restrict__ xT,
    const uint4* __restrict__ tab,
    const short8* __restrict__ wAf,
    const float* __restrict__ shape,
    const float* __restrict__ wo,
    float* __restrict__ out)
{
    __shared__ __align__(16) char smem[59904];
    char*   s_stg = smem;                      // [340 px][128B] 43520 B (swizzled)
    short8* bufB  = (short8*)(smem + 43520);   // [2][8][64]     16384 B

    const int tid = threadIdx.x;
    const int bid = blockIdx.x;                    // 512 blocks
    const int tile = (bid & 7) * 64 + (bid >> 3);  // XCD-chunked swizzle
    const int wh = tile & 1;
    const int h  = (tile >> 1) & 127;
    const int n  = tile >> 8;
    const int w0 = wh * 64;
    const int ybase = h - 2, xbase = w0 - 2;

    const int wave = tid >> 6;
    const int lane = tid & 63;
    const int pxh  = wave & 1;
    const int ksl  = wave >> 1;              // 0..3
    const int bpx  = pxh * 32 + (lane & 31); // build pixel (block-local)
    const int koct = lane >> 5;
    const int chnk = 2 * ksl + koct;         // 16B chunk within 128B dg-row
    const int mt   = wave;                   // consumer m-tile32

    const char* xb = (const char*)xT + (size_t)n * HW * 512;
    const uint4* tb = tab + (size_t)tile * (DGN * K2 * 64);

    f32x16 acc0, acc1;
    #pragma unroll
    for (int r = 0; r < 16; ++r) { acc0[r] = 0.f; acc1[r] = 0.f; }

    // ---- stage dg window: 340 px x 128B, swizzled chunks ----
    auto stageDG = [&](int dg) {
        const char* xsrc = xb + dg * 128;
        for (int i = tid; i < WPX * 8; i += 512) {
            int chunk = i & 7;
            int px = i >> 3;
            int sy = (unsigned)px / WCOLS;
            int sx = px - sy * WCOLS;
            int r = min(max(ybase + sy, 0), HH - 1);
            int c = min(max(xbase + sx, 0), WW - 1);
            short8 v = *(const short8*)(xsrc + (size_t)(r * WW + c) * 512 + chunk * 16);
            *(short8*)(s_stg + px * 128 + ((chunk ^ (px & 7)) * 16)) = v;
        }
    };

    // fast-path corner reads from LDS window (pl0 from table)
    auto stgRead = [&](unsigned meta, short8 S[4]) {
        int pl0 = (int)(meta & 0xFFFFu);
        #pragma unroll
        for (int j = 0; j < 4; ++j) {
            int p = pl0 + ((j >> 1) * WCOLS) + (j & 1);
            S[j] = *(const short8*)(s_stg + p * 128 + ((chnk ^ (p & 7)) << 4));
        }
    };

    // cold path: lanes with escape bit recompute fully + global gather
    auto escFix = [&](int dg, int tapb, unsigned meta,
                      unsigned& w01u, unsigned& w23u, short8 S[4]) {
        if (__ballot(meta >> 31)) {
            if (meta >> 31) {
                int wpix = w0 + bpx;
                float s0 = shape[((size_t)(n * 2 + 0)) * HW + h * WW + wpix];
                float s1 = shape[((size_t)(n * 2 + 1)) * HW + h * WW + wpix];
                int dgkb = dg * 9 + tapb;
                float dy = wo[dgkb * 4 + 0] * s0 + wo[dgkb * 4 + 1] * s1;
                float dx = wo[dgkb * 4 + 2] * s0 + wo[dgkb * 4 + 3] * s1;
                float py  = (float)(h + (tapb / 3) - 1) + dy;
                float pxf = (float)(wpix + (tapb % 3) - 1) + dx;
                float y0f = floorf(py), x0f = floorf(pxf);
                float ly = py - y0f, lx = pxf - x0f;
                int y0 = (int)y0f, x0 = (int)x0f;
                float wg[4] = {(1.f - ly) * (1.f - lx), (1.f - ly) * lx,
                               ly * (1.f - lx),         ly * lx};
                unsigned cw[4];
                #pragma unroll
                for (int j = 0; j < 4; ++j) {
                    int yi = y0 + (j >> 1);
                    int xi = x0 + (j & 1);
                    bool valid = (yi >= 0) && (yi < HH) && (xi >= 0) && (xi < WW);
                    int yc = min(max(yi, 0), HH - 1);
                    int xc = min(max(xi, 0), WW - 1);
                    cw[j] = f2h_u(valid ? wg[j] : 0.0f);
                    S[j] = *(const short8*)(xb + (size_t)(yc * WW + xc) * 512 + dg * 128 + chnk * 16);
                }
                w01u = cw[0] | (cw[1] << 16);
                w23u = cw[2] | (cw[3] << 16);
            }
        }
    };

    auto blendWrite = [&](unsigned w01u, unsigned w23u, const short8 S[4], int slotW) {
        __half2 p01 = __builtin_bit_cast(__half2, w01u);
        __half2 p23 = __builtin_bit_cast(__half2, w23u);
        __half2 c0 = __low2half2(p01), c1 = __high2half2(p01);
        __half2 c2 = __low2half2(p23), c3 = __high2half2(p23);
        H2x4 a0 = __builtin_bit_cast(H2x4, S[0]);
        H2x4 a1 = __builtin_bit_cast(H2x4, S[1]);
        H2x4 a2 = __builtin_bit_cast(H2x4, S[2]);
        H2x4 a3 = __builtin_bit_cast(H2x4, S[3]);
        H2x4 r;
        #pragma unroll
        for (int j = 0; j < 4; ++j) {
            __half2 t = __hmul2(c0, a0.h[j]);
            t = __hfma2(c1, a1.h[j], t);
            t = __hfma2(c2, a2.h[j], t);
            t = __hfma2(c3, a3.h[j], t);
            r.h[j] = t;
        }
        bufB[(slotW * 8 + pxh * 4 + ksl) * 64 + lane] = __builtin_bit_cast(short8, r);
    };

    auto loadA = [&](int i, short8 A[4]) {
        const short8* wa = wAf + ((size_t)(i * 4) * NMT32 + mt) * 64 + lane;
        A[0] = wa[0];
        A[1] = wa[NMT32 * 64];
        A[2] = wa[2 * NMT32 * 64];
        A[3] = wa[3 * NMT32 * 64];
    };

    // ---- table stream (2-builds-ahead) + A(0) ----
    uint4 Tc = tb[0 * 64 + bpx];
    uint4 Tn = tb[1 * 64 + bpx];
    short8 A[4];
    loadA(0, A);

    for (int dg = 0; dg < DGN; ++dg) {
        stageDG(dg);
        RAWBAR();
        // prologue build: k-pair dg*9 (tapb=0) -> bufB slot 0
        {
            short8 S[4];
            stgRead(Tc.x, S);
            uint4 Tnew = tb[(dg * 9 + 2) * 64 + bpx];   // always < 36
            unsigned w01u = Tc.y, w23u = Tc.z;
            escFix(dg, 0, Tc.x, w01u, w23u, S);
            blendWrite(w01u, w23u, S, 0);
            Tc = Tn; Tn = Tnew;
        }
        RAWBAR();
        for (int tap = 0; tap < 9; ++tap) {
            const int i = dg * 9 + tap;
            const int slot = tap & 1;
            const bool hb = (tap < 8);
            // hoisted bufB reads (consumed by MFMA)
            f16x8 br[8];
            #pragma unroll
            for (int f = 0; f < 8; ++f)
                br[f] = __builtin_bit_cast(f16x8, bufB[(slot * 8 + f) * 64 + lane]);
            // S reads for build i+1 stay in flight across the MFMAs
            short8 S[4];
            uint4 Tnew = Tc;
            if (hb) {
                stgRead(Tc.x, S);
                if (i + 3 < NKP) Tnew = tb[(i + 3) * 64 + bpx];
            }
            SB0();
            __builtin_amdgcn_s_setprio(1);
            #pragma unroll
            for (int s = 0; s < 4; ++s) {
                f16x8 a = __builtin_bit_cast(f16x8, A[s]);
                acc0 = __builtin_amdgcn_mfma_f32_32x32x16_f16(a, br[s],     acc0, 0, 0, 0);
                acc1 = __builtin_amdgcn_mfma_f32_32x32x16_f16(a, br[4 + s], acc1, 0, 0, 0);
            }
            __builtin_amdgcn_s_setprio(0);
            SB0();
            if (i + 1 < NKP) loadA(i + 1, A);
            if (hb) {
                unsigned w01u = Tc.y, w23u = Tc.z;
                escFix(dg, tap + 1, Tc.x, w01u, w23u, S);
                blendWrite(w01u, w23u, S, slot ^ 1);
                Tc = Tn; Tn = Tnew;
            }
            RAWBAR();
        }
    }

    // ---- epilogue: direct coalesced stores (32x32 C/D layout) ----
    const int cl = lane & 31;
    const int rb = 4 * (lane >> 5);
    float* on = out + ((size_t)(n * COUT + mt * 32)) * HW + h * WW + w0;
    #pragma unroll
    for (int reg = 0; reg < 16; ++reg) {
        int m = (reg & 3) + 8 * (reg >> 2) + rb;
        on[(size_t)m * HW + cl]      = fmaxf(acc0[reg], 0.f);
        on[(size_t)m * HW + 32 + cl] = fmaxf(acc1[reg], 0.f);
    }
}

extern "C" void kernel_launch(void* const* d_in, const int* in_sizes, int n_in,
                              void* d_out, int out_size, void* d_ws, size_t ws_size,
                              hipStream_t stream) {
    const float* x        = (const float*)d_in[0];
    const float* shape    = (const float*)d_in[1];
    const float* w_offset = (const float*)d_in[2];
    const float* w_adapt  = (const float*)d_in[3];
    float* out = (float*)d_out;

    // ws layout: wA 1.18MB @0 | xT 16.78MB @0x130000 | tab 18.87MB @0x1130000 (~35.2MB total)
    unsigned int*   wA  = (unsigned int*)d_ws;
    unsigned short* xT  = (unsigned short*)((char*)d_ws + 0x130000);
    uint4*          tab = (uint4*)((char*)d_ws + 0x1130000);

    tr_kernel<<<NBATCH * 4 * 256, 256, 0, stream>>>(x, xT);
    int wa_elems = NKS * NMT32 * 64 * 4;
    wa_kernel<<<(wa_elems + 255) / 256, 256, 0, stream>>>(w_adapt, wA);
    coord_kernel<<<NBATCH * HH * 2, 256, 0, stream>>>(shape, w_offset, tab);
    deform_mfma_kernel<<<NBATCH * HH * 2, 512, 0, stream>>>(
        xT, tab, (const short8*)wA, shape, w_offset, out);
}